// Round 1
// 532.905 us; speedup vs baseline: 1.0855x; 1.0855x over previous
//
#include <hip/hip_runtime.h>
#include <cstdint>

// Problem constants
#define TOKENS 16384      // BATCH(8) * SEQ(2048)
#define DMODEL 1024
#define NHEADS 16
#define HDIM   64

typedef __bf16  bf16x8 __attribute__((ext_vector_type(8)));
typedef ushort  u16x8  __attribute__((ext_vector_type(8)));
typedef float   f32x4  __attribute__((ext_vector_type(4)));

// fp32 -> bf16 (round-half-up; inputs are well-scaled normals, no overflow risk)
__device__ __forceinline__ ushort f2bf(float f) {
    union { float f; unsigned int i; } v; v.f = f;
    return (ushort)((v.i + 0x8000u) >> 16);
}
__device__ __forceinline__ f32x4 mfma16(bf16x8 a, bf16x8 b, f32x4 c) {
    return __builtin_amdgcn_mfma_f32_16x16x32_bf16(a, b, c, 0, 0, 0);
}
// async global->LDS direct copy, 16B per lane. LDS dest must be linear in lane.
__device__ __forceinline__ void gload_lds16(const void* g, void* l) {
    __builtin_amdgcn_global_load_lds(
        (const __attribute__((address_space(1))) unsigned int*)(uintptr_t)g,
        (__attribute__((address_space(3))) unsigned int*)(uintptr_t)l,
        16, 0, 0);
}

// ---------------------------------------------------------------------------
// Elementwise fp32 -> bf16 convert, up to 4 tensors via blockIdx.y.
// 256 threads x 8 elems; grids sized to cover exactly (n multiple of 2048).
// ---------------------------------------------------------------------------
struct CvtArgs {
    const float* src[4];
    ushort*      dst[4];
};

__global__ __launch_bounds__(256) void cvt_f32_bf16(CvtArgs a)
{
    const float* __restrict__ s = a.src[blockIdx.y];
    ushort*      __restrict__ d = a.dst[blockIdx.y];
    const long i = ((long)blockIdx.x * 256 + threadIdx.x) * 8;
    const f32x4 v0 = *(const f32x4*)(s + i);
    const f32x4 v1 = *(const f32x4*)(s + i + 4);
    u16x8 p;
    #pragma unroll
    for (int j = 0; j < 4; j++) {
        p[j]     = f2bf(v0[j]);
        p[4 + j] = f2bf(v1[j]);
    }
    *(u16x8*)(d + i) = p;
}

// ---------------------------------------------------------------------------
// NT GEMM:  C[m,n] = sum_k A[m,k] * W[n,k] + bias[n]
// bf16 inputs (pre-converted), fp32 output; bf16 MFMA with fp32 accumulation.
// m97 structure: 128x128 tile, BK=32, 256 threads = 4 waves (2x2),
// global_load_lds width=16 staging (linear LDS), 2 barriers per K-step.
// ---------------------------------------------------------------------------
#define BM 128
#define BN 128
#define BK 32

struct GemmArgs {
    const ushort* A[3];
    const ushort* W[3];
    const float*  Bi[3];
    float*        C[3];
};

__global__ __launch_bounds__(256) void gemm_bt_bias(GemmArgs args, int N, int K)
{
    __shared__ __align__(16) ushort As[BM * BK];   // 8 KB
    __shared__ __align__(16) ushort Bs[BN * BK];   // 8 KB

    const int z = blockIdx.z;
    const ushort* __restrict__ A  = args.A[z];
    const ushort* __restrict__ W  = args.W[z];
    const float*  __restrict__ Bi = args.Bi[z];
    float*        __restrict__ C  = args.C[z];

    const int tid  = threadIdx.x;
    const int wave = tid >> 6;
    const int lane = tid & 63;
    const int wm = wave >> 1;          // 0..1 row-wave
    const int wn = wave & 1;           // 0..1 col-wave
    const long rowBase = (long)blockIdx.y * BM;
    const int  colBase = blockIdx.x * BN;

    // staging: chunk c (0..511) covers row c>>2, k-elems (c&3)*8 (16B each).
    // LDS byte offset = c*16 => within a wave, linear in lane (HW requirement).
    const int c0  = tid;
    const int c1  = tid + 256;
    const int r0s = c0 >> 2, k0s = (c0 & 3) * 8;
    const int r1s = c1 >> 2, k1s = (c1 & 3) * 8;

    // fragment addressing
    const int fr = lane & 15;          // m (A) / n (B)
    const int fk = (lane >> 4) * 8;    // k offset

    f32x4 acc[4][4];
    #pragma unroll
    for (int i = 0; i < 4; i++)
        #pragma unroll
        for (int j = 0; j < 4; j++)
            acc[i][j] = (f32x4){0.f, 0.f, 0.f, 0.f};

    for (int kt = 0; kt < K; kt += BK) {
        __syncthreads();  // previous tile's ds_reads done before overwrite
        gload_lds16(A + (rowBase + r0s) * (long)K + kt + k0s, &As[c0 * 8]);
        gload_lds16(A + (rowBase + r1s) * (long)K + kt + k1s, &As[c1 * 8]);
        gload_lds16(W + (long)(colBase + r0s) * K + kt + k0s, &Bs[c0 * 8]);
        gload_lds16(W + (long)(colBase + r1s) * K + kt + k1s, &Bs[c1 * 8]);
        __syncthreads();  // drains vmcnt(0): staged tile visible to all waves

        bf16x8 af[4], bfv[4];
        #pragma unroll
        for (int i = 0; i < 4; i++)
            af[i] = *(const bf16x8*)&As[(wm * 64 + i * 16 + fr) * BK + fk];
        #pragma unroll
        for (int j = 0; j < 4; j++)
            bfv[j] = *(const bf16x8*)&Bs[(wn * 64 + j * 16 + fr) * BK + fk];

        #pragma unroll
        for (int i = 0; i < 4; i++)
            #pragma unroll
            for (int j = 0; j < 4; j++)
                acc[i][j] = mfma16(af[i], bfv[j], acc[i][j]);
    }

    // epilogue: C layout col=lane&15, row=(lane>>4)*4+reg; fp32 stores
    const int qd = lane >> 4;
    #pragma unroll
    for (int j = 0; j < 4; j++) {
        const int col = colBase + wn * 64 + j * 16 + fr;
        const float bv = Bi[col];
        #pragma unroll
        for (int i = 0; i < 4; i++) {
            const long r0 = rowBase + wm * 64 + i * 16 + qd * 4;
            #pragma unroll
            for (int r = 0; r < 4; r++)
                C[(r0 + r) * (long)N + col] = acc[i][j][r] + bv;
        }
    }
}

// ---------------------------------------------------------------------------
// Fused per-token attention (16x16 head-gram) + LayerNorm. Pure VALU, fp32.
// One wave per token; 4 tokens per 256-thread block.
// Output is written as bf16 (feeds the bf16 output-projection GEMM directly;
// identical rounding to what that GEMM's staging previously applied).
// ---------------------------------------------------------------------------
#define PADQ 68   // float stride for Qs/Ks rows (16 heads x 64 dims, +4 pad)

__global__ __launch_bounds__(256) void attn_ln_valu(
    const float* __restrict__ Q, const float* __restrict__ Kp,
    const float* __restrict__ V,
    const float* __restrict__ lng, const float* __restrict__ lnb,
    ushort* __restrict__ O)
{
    __shared__ float Qs[4][16 * PADQ];
    __shared__ float Ks[4][16 * PADQ];
    __shared__ float Vs[4][16 * 64];
    __shared__ __align__(16) float Pt[4][256];      // Pt[g*16+h]
    __shared__ float lg[DMODEL], lb[DMODEL];

    const int tid  = threadIdx.x;
    const int w    = tid >> 6;
    const int lane = tid & 63;
    const long tok  = (long)blockIdx.x * 4 + w;
    const long base = tok * DMODEL;

    // stage LN params (block-shared): 256 threads x 4 floats
    ((f32x4*)lg)[tid] = ((const f32x4*)lng)[tid];
    ((f32x4*)lb)[tid] = ((const f32x4*)lnb)[tid];

    // stage Q,K,V: lane covers head row = lane>>2, dims d0..d0+15
    {
        const int row = lane >> 2;
        const int d0  = (lane & 3) * 16;
        const long go = base + row * HDIM + d0;
        #pragma unroll
        for (int c = 0; c < 4; c++) {
            const f32x4 q = *(const f32x4*)(Q  + go + c * 4);
            const f32x4 k = *(const f32x4*)(Kp + go + c * 4);
            const f32x4 v = *(const f32x4*)(V  + go + c * 4);
            #pragma unroll
            for (int i = 0; i < 4; i++) {
                Qs[w][row * PADQ + d0 + c * 4 + i] = q[i];
                Ks[w][row * PADQ + d0 + c * 4 + i] = k[i];
                Vs[w][row * 64  + d0 + c * 4 + i]  = v[i];
            }
        }
    }
    __syncthreads();

    // energy[h][g] = sum_d Q[h][d]*K[g][d]; lane owns g=lane&15, h=quad*4+r
    const int g  = lane & 15;
    const int hq = lane >> 4;
    float p[4];
    #pragma unroll
    for (int r = 0; r < 4; r++) {
        const int h = hq * 4 + r;
        const float* qrow = &Qs[w][h * PADQ];   // broadcast within 16-lane group
        const float* krow = &Ks[w][g * PADQ];
        float e = 0.f;
        #pragma unroll
        for (int d = 0; d < HDIM; d++) e += qrow[d] * krow[d];

        // softmax over g: reduce across the 16 lanes of this quad-group
        float x = e * 0.03125f;                      // 1/sqrt(1024)
        float mx = x;
        #pragma unroll
        for (int m = 1; m < 16; m <<= 1) mx = fmaxf(mx, __shfl_xor(mx, m, 64));
        float ex = __expf(x - mx);
        float sm = ex;
        #pragma unroll
        for (int m = 1; m < 16; m <<= 1) sm += __shfl_xor(sm, m, 64);
        p[r] = ex / sm;
    }
    // store P transposed: Pt[g*16 + h] (16B-aligned vector store)
    *(f32x4*)&Pt[w][g * 16 + hq * 4] = (f32x4){p[0], p[1], p[2], p[3]};

    __syncthreads();

    // PV: lane <-> d; out[h] = sum_g P[h][g] * V[g][lane]
    float out[NHEADS];
    #pragma unroll
    for (int h = 0; h < NHEADS; h++) out[h] = 0.f;
    #pragma unroll
    for (int gg = 0; gg < 16; gg++) {
        const float vr = Vs[w][gg * 64 + lane];
        const f32x4* prow = (const f32x4*)&Pt[w][gg * 16];
        #pragma unroll
        for (int j = 0; j < 4; j++) {
            const f32x4 pj = prow[j];   // broadcast read, conflict-free
            out[j * 4 + 0] += pj[0] * vr;
            out[j * 4 + 1] += pj[1] * vr;
            out[j * 4 + 2] += pj[2] * vr;
            out[j * 4 + 3] += pj[3] * vr;
        }
    }

    // LayerNorm over 1024 = 16 regs x 64 lanes
    float s1 = 0.f, s2 = 0.f;
    #pragma unroll
    for (int h = 0; h < NHEADS; h++) { s1 += out[h]; s2 += out[h] * out[h]; }
    #pragma unroll
    for (int m = 1; m < 64; m <<= 1) {
        s1 += __shfl_xor(s1, m, 64);
        s2 += __shfl_xor(s2, m, 64);
    }
    const float mu  = s1 * (1.f / DMODEL);
    const float var = s2 * (1.f / DMODEL) - mu * mu;
    const float rstd = rsqrtf(var + 1e-5f);

    #pragma unroll
    for (int h = 0; h < NHEADS; h++) {
        const int i = h * HDIM + lane;
        O[base + i] = f2bf((out[h] - mu) * rstd * lg[i] + lb[i]);
    }
}

// ---------------------------------------------------------------------------
// launch — ws-size-adaptive chunked pipeline.
// ws layout: [4x bf16 weights | per-chunk: qb,kb,vb (bf16) | qp,vp (fp32)]
// kp (fp32 K-proj) borrows the d_out chunk (dead before final GEMM overwrite);
// attention writes bf16 output over qb (dead after GEMM1).
// ---------------------------------------------------------------------------
extern "C" void kernel_launch(void* const* d_in, const int* in_sizes, int n_in,
                              void* d_out, int out_size, void* d_ws, size_t ws_size,
                              hipStream_t stream)
{
    const float* query = (const float*)d_in[0];
    const float* key   = (const float*)d_in[1];
    const float* value = (const float*)d_in[2];
    const float* Wq = (const float*)d_in[3];
    const float* bq = (const float*)d_in[4];
    const float* Wk = (const float*)d_in[5];
    const float* bk = (const float*)d_in[6];
    const float* Wv = (const float*)d_in[7];
    const float* bv = (const float*)d_in[8];
    const float* lng = (const float*)d_in[9];
    const float* lnb = (const float*)d_in[10];
    const float* Wo = (const float*)d_in[11];
    const float* bo = (const float*)d_in[12];
    float* out = (float*)d_out;

    const long WELEMS = (long)DMODEL * DMODEL;       // 1Mi elems per weight

    ushort* wq_b = (ushort*)d_ws;
    ushort* wk_b = wq_b + WELEMS;
    ushort* wv_b = wk_b + WELEMS;
    ushort* wo_b = wv_b + WELEMS;
    ushort* cbuf = wo_b + WELEMS;                    // per-chunk region

    // bytes needed: 8MB weights + CM*1024*(3*2B bf16 + 2*4B fp32) = 8MB + CM*14336
    int NC = 1;
    while (NC < 128 &&
           (size_t)(8 * WELEMS) + (size_t)(TOKENS / NC) * DMODEL * 14 > ws_size)
        NC <<= 1;
    const int CM = TOKENS / NC;                 // tokens per chunk (mult of 128)
    const size_t CE = (size_t)CM * DMODEL;      // elems per chunk buffer

    ushort* qb = cbuf;            // query bf16; later reused for attn bf16 out
    ushort* kb = qb + CE;
    ushort* vb = kb + CE;
    float*  qp = (float*)(vb + CE);   // fp32 Q-projection (attn input)
    float*  vp = qp + CE;             // fp32 V-projection (attn input)

    // 0) convert weights fp32 -> bf16 (once)
    {
        CvtArgs cw;
        cw.src[0] = Wq; cw.src[1] = Wk; cw.src[2] = Wv; cw.src[3] = Wo;
        cw.dst[0] = wq_b; cw.dst[1] = wk_b; cw.dst[2] = wv_b; cw.dst[3] = wo_b;
        cvt_f32_bf16<<<dim3((unsigned)(WELEMS / 2048), 4), 256, 0, stream>>>(cw);
    }

    for (int c = 0; c < NC; ++c) {
        const size_t off = (size_t)c * CE;
        float* kp = out + off;                  // fp32 scratch in d_out chunk

        // 1) convert this chunk's query/key/value fp32 -> bf16
        {
            CvtArgs ci;
            ci.src[0] = query + off; ci.src[1] = key + off; ci.src[2] = value + off;
            ci.src[3] = query;  // unused (z<3)
            ci.dst[0] = qb; ci.dst[1] = kb; ci.dst[2] = vb; ci.dst[3] = qb;
            cvt_f32_bf16<<<dim3((unsigned)(CE / 2048), 3), 256, 0, stream>>>(ci);
        }

        // 2) fused QKV projections for this chunk (z picks q/k/v)
        GemmArgs g1;
        g1.A[0] = qb;    g1.A[1] = kb;   g1.A[2] = vb;
        g1.W[0] = wq_b;  g1.W[1] = wk_b; g1.W[2] = wv_b;
        g1.Bi[0] = bq;   g1.Bi[1] = bk;  g1.Bi[2] = bv;
        g1.C[0] = qp;    g1.C[1] = kp;   g1.C[2] = vp;
        gemm_bt_bias<<<dim3(DMODEL / BN, CM / BM, 3), 256, 0, stream>>>(
            g1, DMODEL, DMODEL);

        // 3) per-token attention + LayerNorm -> bf16 into qb (dead after GEMM1)
        attn_ln_valu<<<CM / 4, 256, 0, stream>>>(qp, kp, vp, lng, lnb, qb);

        // 4) output projection -> d_out chunk (overwrites kp scratch)
        GemmArgs g2;
        g2.A[0] = g2.A[1] = g2.A[2] = qb;
        g2.W[0] = g2.W[1] = g2.W[2] = wo_b;
        g2.Bi[0] = g2.Bi[1] = g2.Bi[2] = bo;
        g2.C[0] = g2.C[1] = g2.C[2] = out + off;
        gemm_bt_bias<<<dim3(DMODEL / BN, CM / BM, 1), 256, 0, stream>>>(
            g2, DMODEL, DMODEL);
    }
}

// Round 2
// 457.396 us; speedup vs baseline: 1.2648x; 1.1651x over previous
//
#include <hip/hip_runtime.h>
#include <cstdint>

// Problem constants
#define TOKENS 16384      // BATCH(8) * SEQ(2048)
#define DMODEL 1024
#define NHEADS 16
#define HDIM   64

typedef __bf16  bf16x8 __attribute__((ext_vector_type(8)));
typedef ushort  u16x8  __attribute__((ext_vector_type(8)));
typedef ushort  u16x4  __attribute__((ext_vector_type(4)));
typedef float   f32x4  __attribute__((ext_vector_type(4)));

// fp32 -> bf16 (round-half-up; inputs are well-scaled normals, no overflow risk)
__device__ __forceinline__ ushort f2bf(float f) {
    union { float f; unsigned int i; } v; v.f = f;
    return (ushort)((v.i + 0x8000u) >> 16);
}
__device__ __forceinline__ f32x4 mfma16(bf16x8 a, bf16x8 b, f32x4 c) {
    return __builtin_amdgcn_mfma_f32_16x16x32_bf16(a, b, c, 0, 0, 0);
}
// async global->LDS direct copy, 16B per lane. LDS dest must be linear in lane.
__device__ __forceinline__ void gload_lds16(const void* g, void* l) {
    __builtin_amdgcn_global_load_lds(
        (const __attribute__((address_space(1))) unsigned int*)(uintptr_t)g,
        (__attribute__((address_space(3))) unsigned int*)(uintptr_t)l,
        16, 0, 0);
}
union BU { u16x8 u; bf16x8 b; };

// ---------------------------------------------------------------------------
// Elementwise fp32 -> bf16 convert, up to 4 tensors via blockIdx.y.
// ---------------------------------------------------------------------------
struct CvtArgs {
    const float* src[4];
    ushort*      dst[4];
};

__global__ __launch_bounds__(256) void cvt_f32_bf16(CvtArgs a)
{
    const float* __restrict__ s = a.src[blockIdx.y];
    ushort*      __restrict__ d = a.dst[blockIdx.y];
    const long i = ((long)blockIdx.x * 256 + threadIdx.x) * 8;
    const f32x4 v0 = *(const f32x4*)(s + i);
    const f32x4 v1 = *(const f32x4*)(s + i + 4);
    u16x8 p;
    #pragma unroll
    for (int j = 0; j < 4; j++) {
        p[j]     = f2bf(v0[j]);
        p[4 + j] = f2bf(v1[j]);
    }
    *(u16x8*)(d + i) = p;
}

// ---------------------------------------------------------------------------
// NT GEMM:  C[m,n] = sum_k A[m,k] * W[n,k] + bias[n]
// bf16 inputs; bf16 or fp32 output (template). MFMA fp32 accumulation.
// 128x128 tile, BK=32, 256 threads = 4 waves (2x2), global_load_lds width=16.
// 2-phase double-buffer (T3 minimum): stage tile t+1 while computing tile t,
// ONE barrier per K-step (its vmcnt/lgkm drain covers both hazards).
// XCD-chunked blockIdx swizzle (T1): the 8 column-blocks sharing an A-panel
// run consecutively on the same XCD -> A re-reads become L2 hits.
// ---------------------------------------------------------------------------
#define BM 128
#define BN 128
#define BK 32

struct GemmArgs {
    const ushort* A[3];
    const ushort* W[3];
    const float*  Bi[3];
    void*         C[3];
};

template<int BF16OUT>
__global__ __launch_bounds__(256) void gemm_bt_bias(GemmArgs args, int N, int K)
{
    __shared__ __align__(16) ushort As[2][BM * BK];   // 2 x 8 KB
    __shared__ __align__(16) ushort Bs[2][BN * BK];   // 2 x 8 KB

    // XCD-chunked swizzle (bijective: total % 8 == 0 since gridDim.x == 8)
    const int gx = gridDim.x, gy = gridDim.y;
    const int lin   = (blockIdx.z * gy + blockIdx.y) * gx + blockIdx.x;
    const int total = gx * gy * gridDim.z;
    const int cpx   = total >> 3;
    const int swz   = (lin & 7) * cpx + (lin >> 3);
    const int bz    = swz / (gx * gy);
    const int rem   = swz - bz * gx * gy;
    const int by    = rem / gx;
    const int bx    = rem - by * gx;

    const ushort* __restrict__ A  = args.A[bz];
    const ushort* __restrict__ W  = args.W[bz];
    const float*  __restrict__ Bi = args.Bi[bz];

    const int tid  = threadIdx.x;
    const int wave = tid >> 6;
    const int lane = tid & 63;
    const int wm = wave >> 1;          // 0..1 row-wave
    const int wn = wave & 1;           // 0..1 col-wave
    const long rowBase = (long)by * BM;
    const long colBase = (long)bx * BN;

    // staging: chunk c (0..511) covers row c>>2, k-elems (c&3)*8 (16B each).
    // LDS byte offset = c*16 => within a wave, linear in lane (HW requirement).
    const int c0  = tid;
    const int c1  = tid + 256;
    const int r0s = c0 >> 2, k0s = (c0 & 3) * 8;
    const int r1s = c1 >> 2, k1s = (c1 & 3) * 8;

    // fragment addressing
    const int fr = lane & 15;          // m (A) / n (B)
    const int fk = (lane >> 4) * 8;    // k offset

    f32x4 acc[4][4];
    #pragma unroll
    for (int i = 0; i < 4; i++)
        #pragma unroll
        for (int j = 0; j < 4; j++)
            acc[i][j] = (f32x4){0.f, 0.f, 0.f, 0.f};

    auto STAGE = [&](int b, int kt) {
        gload_lds16(A + (rowBase + r0s) * (long)K + kt + k0s, &As[b][c0 * 8]);
        gload_lds16(A + (rowBase + r1s) * (long)K + kt + k1s, &As[b][c1 * 8]);
        gload_lds16(W + (colBase + r0s) * (long)K + kt + k0s, &Bs[b][c0 * 8]);
        gload_lds16(W + (colBase + r1s) * (long)K + kt + k1s, &Bs[b][c1 * 8]);
    };

    const int nt = K / BK;
    int cur = 0;
    STAGE(0, 0);
    __syncthreads();   // compiler drains vmcnt(0) before barrier: tile 0 ready

    for (int t = 0; t < nt; ++t) {
        if (t + 1 < nt) STAGE(cur ^ 1, (t + 1) * BK);   // prefetch next tile

        bf16x8 af[4], bfv[4];
        #pragma unroll
        for (int i = 0; i < 4; i++)
            af[i] = *(const bf16x8*)&As[cur][(wm * 64 + i * 16 + fr) * BK + fk];
        #pragma unroll
        for (int j = 0; j < 4; j++)
            bfv[j] = *(const bf16x8*)&Bs[cur][(wn * 64 + j * 16 + fr) * BK + fk];

        #pragma unroll
        for (int i = 0; i < 4; i++)
            #pragma unroll
            for (int j = 0; j < 4; j++)
                acc[i][j] = mfma16(af[i], bfv[j], acc[i][j]);

        __syncthreads();   // drains lgkm (our reads) + vmcnt (next tile) once
        cur ^= 1;
    }

    // epilogue: C layout col=lane&15, row=(lane>>4)*4+reg
    const int qd = lane >> 4;
    #pragma unroll
    for (int j = 0; j < 4; j++) {
        const long col = colBase + wn * 64 + j * 16 + fr;
        const float bv = Bi[col];
        #pragma unroll
        for (int i = 0; i < 4; i++) {
            const long r0 = rowBase + wm * 64 + i * 16 + qd * 4;
            #pragma unroll
            for (int r = 0; r < 4; r++) {
                const float val = acc[i][j][r] + bv;
                if (BF16OUT)
                    ((ushort*)args.C[bz])[(r0 + r) * (long)N + col] = f2bf(val);
                else
                    ((float*)args.C[bz])[(r0 + r) * (long)N + col] = val;
            }
        }
    }
}

// ---------------------------------------------------------------------------
// Fused per-token attention (16x16 head-gram) + LayerNorm — MFMA version.
// One wave per token; 4 tokens per 256-thread block. bf16 in, bf16 out.
//   QK^T: 2x mfma 16x16x32 (A=Q rows, B=K rows, fragments direct from global)
//   softmax over g: 16-lane shfl reduce (E layout col=g, row=h — verified)
//   PV:   4x mfma 16x16x32 (A=P via LDS transpose bounce, k 16..31 zero-pad;
//         B=V from LDS rows, zeroed for k>=16 lanes)
//   LN:   lane holds out[h=(l>>4)*4+r][d=dblk*16+(l&15)] — full 64-lane reduce
// ---------------------------------------------------------------------------
__global__ __launch_bounds__(256) void attn_ln_mfma(
    const ushort* __restrict__ Qp, const ushort* __restrict__ Kp,
    const ushort* __restrict__ Vp,
    const float* __restrict__ lng, const float* __restrict__ lnb,
    ushort* __restrict__ O)
{
    __shared__ __align__(16) ushort Vs[4][16 * 64];   // per-wave V rows [g][d]
    __shared__ __align__(16) ushort Pm[4][16 * 32];   // per-wave P [h][k], k<16 live

    const int tid  = threadIdx.x;
    const int w    = tid >> 6;
    const int lane = tid & 63;
    const long tok  = (long)blockIdx.x * 4 + w;
    const long base = tok * DMODEL;

    // stage V (row-major [g][d]) via direct global->LDS, linear in lane
    gload_lds16(Vp + base +       lane * 8, &Vs[w][      lane * 8]);
    gload_lds16(Vp + base + 512 + lane * 8, &Vs[w][512 + lane * 8]);

    // zero the k=16..31 half of Pm: lane covers row lane&15, cols 16+(l>>4)*4..+3
    *(u16x4*)&Pm[w][(lane & 15) * 32 + 16 + (lane >> 4) * 4] = (u16x4){0, 0, 0, 0};

    const int fr = lane & 15;          // g (QK cols) / h (P rows on read)
    const int fs = (lane >> 4) * 8;    // k-slice

    // QK^T fragments directly from global (token row is 2KB, L2/LLC-resident)
    const bf16x8 aq0 = *(const bf16x8*)(Qp + base + fr * 64 + fs);
    const bf16x8 aq1 = *(const bf16x8*)(Qp + base + fr * 64 + fs + 32);
    const bf16x8 bk0 = *(const bf16x8*)(Kp + base + fr * 64 + fs);
    const bf16x8 bk1 = *(const bf16x8*)(Kp + base + fr * 64 + fs + 32);

    f32x4 e = (f32x4){0.f, 0.f, 0.f, 0.f};
    e = mfma16(aq0, bk0, e);
    e = mfma16(aq1, bk1, e);
    // lane holds E[h=(lane>>4)*4+r][g=fr]

    // softmax over g = across the 16 lanes of this quad-group; store P^T to LDS
    #pragma unroll
    for (int r = 0; r < 4; ++r) {
        const float x = e[r] * 0.03125f;              // 1/sqrt(1024)
        float mx = x;
        #pragma unroll
        for (int m = 1; m < 16; m <<= 1) mx = fmaxf(mx, __shfl_xor(mx, m, 64));
        const float ex = __expf(x - mx);
        float sm = ex;
        #pragma unroll
        for (int m = 1; m < 16; m <<= 1) sm += __shfl_xor(sm, m, 64);
        Pm[w][((lane >> 4) * 4 + r) * 32 + fr] = f2bf(ex / sm);
    }

    __syncthreads();   // drains vmcnt (V staging) + lgkm (P writes)

    // PV: A-frag = P[h=fr][k=fs..fs+7] (zero for k>=16); one MFMA per d-block
    const bf16x8 pa = *(const bf16x8*)&Pm[w][fr * 32 + fs];

    f32x4 o[4];
    #pragma unroll
    for (int dblk = 0; dblk < 4; ++dblk) {
        BU bu; bu.u = (u16x8){0, 0, 0, 0, 0, 0, 0, 0};
        if (lane < 32) {   // k = fs+j < 16: real V rows; else stay zero
            #pragma unroll
            for (int j = 0; j < 8; ++j)
                bu.u[j] = Vs[w][(fs + j) * 64 + dblk * 16 + fr];
        }
        o[dblk] = mfma16(pa, bu.b, (f32x4){0.f, 0.f, 0.f, 0.f});
    }
    // lane holds out[h=(lane>>4)*4+r][d=dblk*16+fr]

    // LayerNorm over 1024: 16 regs/lane x 64 lanes cover it exactly once
    float s1 = 0.f, s2 = 0.f;
    #pragma unroll
    for (int dblk = 0; dblk < 4; ++dblk)
        #pragma unroll
        for (int r = 0; r < 4; ++r) { const float v = o[dblk][r]; s1 += v; s2 += v * v; }
    #pragma unroll
    for (int m = 1; m < 64; m <<= 1) {
        s1 += __shfl_xor(s1, m, 64);
        s2 += __shfl_xor(s2, m, 64);
    }
    const float mu   = s1 * (1.f / DMODEL);
    const float var  = s2 * (1.f / DMODEL) - mu * mu;
    const float rstd = rsqrtf(var + 1e-5f);

    #pragma unroll
    for (int dblk = 0; dblk < 4; ++dblk) {
        #pragma unroll
        for (int r = 0; r < 4; ++r) {
            const int h = (lane >> 4) * 4 + r;
            const int i = h * HDIM + dblk * 16 + fr;
            O[base + i] = f2bf((o[dblk][r] - mu) * rstd * lng[i] + lnb[i]);
        }
    }
}

// ---------------------------------------------------------------------------
// launch — ws-size-adaptive chunked pipeline.
// ws layout: [4x bf16 weights | per-chunk: qb,kb,vb,qp,vp (all bf16)]
// kp (bf16 K-proj) borrows the d_out chunk (dead before final GEMM overwrite);
// attention writes bf16 output over qb (dead after GEMM1).
// ---------------------------------------------------------------------------
extern "C" void kernel_launch(void* const* d_in, const int* in_sizes, int n_in,
                              void* d_out, int out_size, void* d_ws, size_t ws_size,
                              hipStream_t stream)
{
    const float* query = (const float*)d_in[0];
    const float* key   = (const float*)d_in[1];
    const float* value = (const float*)d_in[2];
    const float* Wq = (const float*)d_in[3];
    const float* bq = (const float*)d_in[4];
    const float* Wk = (const float*)d_in[5];
    const float* bk = (const float*)d_in[6];
    const float* Wv = (const float*)d_in[7];
    const float* bv = (const float*)d_in[8];
    const float* lng = (const float*)d_in[9];
    const float* lnb = (const float*)d_in[10];
    const float* Wo = (const float*)d_in[11];
    const float* bo = (const float*)d_in[12];
    float* out = (float*)d_out;

    const long WELEMS = (long)DMODEL * DMODEL;       // 1Mi elems per weight

    ushort* wq_b = (ushort*)d_ws;
    ushort* wk_b = wq_b + WELEMS;
    ushort* wv_b = wk_b + WELEMS;
    ushort* wo_b = wv_b + WELEMS;
    ushort* cbuf = wo_b + WELEMS;                    // per-chunk region

    // bytes needed: 8MB weights + CM*1024*(5 bf16 bufs * 2B) = 8MB + CM*10240
    int NC = 1;
    while (NC < 128 &&
           (size_t)(8 * WELEMS) + (size_t)(TOKENS / NC) * DMODEL * 10 > ws_size)
        NC <<= 1;
    const int CM = TOKENS / NC;                 // tokens per chunk (mult of 128)
    const size_t CE = (size_t)CM * DMODEL;      // elems per chunk buffer

    ushort* qb = cbuf;            // query bf16; later reused for attn bf16 out
    ushort* kb = qb + CE;
    ushort* vb = kb + CE;
    ushort* qp = vb + CE;         // bf16 Q-projection (attn input)
    ushort* vp = qp + CE;         // bf16 V-projection (attn input)

    // 0) convert weights fp32 -> bf16 (once)
    {
        CvtArgs cw;
        cw.src[0] = Wq; cw.src[1] = Wk; cw.src[2] = Wv; cw.src[3] = Wo;
        cw.dst[0] = wq_b; cw.dst[1] = wk_b; cw.dst[2] = wv_b; cw.dst[3] = wo_b;
        cvt_f32_bf16<<<dim3((unsigned)(WELEMS / 2048), 4), 256, 0, stream>>>(cw);
    }

    for (int c = 0; c < NC; ++c) {
        const size_t off = (size_t)c * CE;
        ushort* kp = (ushort*)(out + off);      // bf16 scratch in d_out chunk

        // 1) convert this chunk's query/key/value fp32 -> bf16
        {
            CvtArgs ci;
            ci.src[0] = query + off; ci.src[1] = key + off; ci.src[2] = value + off;
            ci.src[3] = query;  // unused (z<3)
            ci.dst[0] = qb; ci.dst[1] = kb; ci.dst[2] = vb; ci.dst[3] = qb;
            cvt_f32_bf16<<<dim3((unsigned)(CE / 2048), 3), 256, 0, stream>>>(ci);
        }

        // 2) fused QKV projections, bf16 outputs (z picks q/k/v)
        GemmArgs g1;
        g1.A[0] = qb;    g1.A[1] = kb;   g1.A[2] = vb;
        g1.W[0] = wq_b;  g1.W[1] = wk_b; g1.W[2] = wv_b;
        g1.Bi[0] = bq;   g1.Bi[1] = bk;  g1.Bi[2] = bv;
        g1.C[0] = qp;    g1.C[1] = kp;   g1.C[2] = vp;
        gemm_bt_bias<1><<<dim3(DMODEL / BN, CM / BM, 3), 256, 0, stream>>>(
            g1, DMODEL, DMODEL);

        // 3) per-token attention + LayerNorm -> bf16 into qb (dead after GEMM1)
        attn_ln_mfma<<<CM / 4, 256, 0, stream>>>(qp, kp, vp, lng, lnb, qb);

        // 4) output projection -> d_out chunk fp32 (overwrites kp scratch)
        GemmArgs g2;
        g2.A[0] = g2.A[1] = g2.A[2] = qb;
        g2.W[0] = g2.W[1] = g2.W[2] = wo_b;
        g2.Bi[0] = g2.Bi[1] = g2.Bi[2] = bo;
        g2.C[0] = g2.C[1] = g2.C[2] = out + off;
        gemm_bt_bias<0><<<dim3(DMODEL / BN, CM / BM, 1), 256, 0, stream>>>(
            g2, DMODEL, DMODEL);
    }
}